// Round 1
// baseline (381.267 us; speedup 1.0000x reference)
//
#include <hip/hip_runtime.h>
#include <math.h>

// Output: 2 * pe[s][c] broadcast over batch; pe[s][c] = sin(div) if c even else cos(div),
// div = s / 10000^(c/16*2) = s * 2^(-c * log2(10000) / 8).
// Total output: 65536*64*16 = 67,108,864 fp32 = 256 MiB. Pure write, input unused.

__global__ __launch_bounds__(256) void pe_broadcast_kernel(float4* __restrict__ out, int total4) {
    const int tid = blockIdx.x * blockDim.x + threadIdx.x;

    // flat float index of this thread's first float4
    const int flat = tid * 4;
    const int s = (flat >> 4) & 63;   // position index 0..63
    const int p = flat & 15;          // channel index of lane's first float (0,4,8,12)

    // Compute the 4 values once; pattern period (1024 floats) divides the grid
    // stride (gridDim*256*4 floats), so each thread's value is loop-invariant.
    float4 v;
    const float LOG2_10000_OVER_8 = 1.6609640474436813f; // log2(10000)/8
    float vals[4];
#pragma unroll
    for (int k = 0; k < 4; ++k) {
        const int c = p + k;
        const float inv_freq = exp2f(-(float)c * LOG2_10000_OVER_8);
        const float div = (float)s * inv_freq;
        const float pe = ((c & 1) == 0) ? sinf(div) : cosf(div);
        vals[k] = 2.0f * pe;
    }
    v.x = vals[0]; v.y = vals[1]; v.z = vals[2]; v.w = vals[3];

    const int stride = gridDim.x * blockDim.x;
    for (int i = tid; i < total4; i += stride) {
        out[i] = v;
    }
}

extern "C" void kernel_launch(void* const* d_in, const int* in_sizes, int n_in,
                              void* d_out, int out_size, void* d_ws, size_t ws_size,
                              hipStream_t stream) {
    (void)d_in; (void)in_sizes; (void)n_in; (void)d_ws; (void)ws_size;
    float4* out = (float4*)d_out;
    const int total4 = out_size / 4;           // 16,777,216 float4s
    const int block = 256;
    // 2048 blocks * 256 threads = 524,288 threads = full residency (256 CU * 2048);
    // each thread stores 32 float4s.
    const int grid = 2048;
    pe_broadcast_kernel<<<grid, block, 0, stream>>>(out, total4);
}